// Round 10
// baseline (438.503 us; speedup 1.0000x reference)
//
#include <hip/hip_runtime.h>
#include <hip/hip_bf16.h>
#include <stdint.h>

#define Bn 256
#define Tn 127
#define Kn 128
#define Hn 256

typedef float f32x4 __attribute__((ext_vector_type(4)));
typedef short s16x8 __attribute__((ext_vector_type(8)));

// ws layout
#define GX_BYTES   66584576ULL   // bf16 [32][127][2][8][4][128]
#define REC_OFF    66584576ULL   // u64 [32 g][2 s][2 parity][512 tid] tagged records
#define REC_BYTES  524288ULL
#define WIH_OFF    (REC_OFF + REC_BYTES)     // bf16 W_ih, 256KB
#define WHH_OFF    (WIH_OFF + 262144ULL)     // bf16 W_hh, 512KB
#define WS_NEED    (WHH_OFF + 524288ULL)

__device__ __forceinline__ float bf2f(unsigned short b){
  union { unsigned u; float f; } v; v.u = ((unsigned)b) << 16; return v.f;
}
__device__ __forceinline__ unsigned short f2bf_rn(float f){
  union { __hip_bfloat16 h; unsigned short s; } u;
  u.h = __float2bfloat16(f);
  return u.s;
}
__device__ __forceinline__ s16x8 cvt8(f32x4 a, f32x4 b){
  union { __hip_bfloat162 h2; unsigned short s[2]; } u0,u1,u2,u3;
  u0.h2 = __float22bfloat162_rn(float2{a[0],a[1]});
  u1.h2 = __float22bfloat162_rn(float2{a[2],a[3]});
  u2.h2 = __float22bfloat162_rn(float2{b[0],b[1]});
  u3.h2 = __float22bfloat162_rn(float2{b[2],b[3]});
  s16x8 r;
  r[0]=(short)u0.s[0]; r[1]=(short)u0.s[1]; r[2]=(short)u1.s[0]; r[3]=(short)u1.s[1];
  r[4]=(short)u2.s[0]; r[5]=(short)u2.s[1]; r[6]=(short)u3.s[0]; r[7]=(short)u3.s[1];
  return r;
}
__device__ __forceinline__ float sigf(float x){ return 1.f/(1.f+__expf(-x)); }
__device__ __forceinline__ float tanh_fast(float x){
  float ax = fabsf(x);
  float e = __expf(-2.f*ax);
  float t = (1.f - e)/(1.f + e);
  return x < 0.f ? -t : t;
}

// ---------------- W conversion: f32 -> bf16, once per launch ----------------
__global__ __launch_bounds__(256) void wconv_kernel(
    const float* __restrict__ Wih, const float* __restrict__ Whh,
    __hip_bfloat16* __restrict__ Bih, __hip_bfloat16* __restrict__ Bhh)
{
  const int i = blockIdx.x*256 + threadIdx.x;   // grid 192*256 = 49152
  const float* src; __hip_bfloat16* dst; int j;
  if (i < 16384){ src = Wih; dst = Bih; j = i; }
  else          { src = Whh; dst = Bhh; j = i - 16384; }
  const f32x4 a = *(const f32x4*)(src + (size_t)j*8);
  const f32x4 b = *(const f32x4*)(src + (size_t)j*8 + 4);
  s16x8 r = cvt8(a, b);
  *(s16x8*)(dst + (size_t)j*8) = r;
}

// ---------------- Phase 0: alpha = softmax(x_score), weight = alpha*input -----
__global__ __launch_bounds__(256) void phase0_kernel(
    const float* __restrict__ in, const float* __restrict__ fc_w,
    float* __restrict__ out)
{
  const int b    = blockIdx.x;
  const int tid  = threadIdx.x;
  const int k    = tid & 127;
  const int half = tid >> 7;
  __shared__ float wx[Tn+1];
  __shared__ float partial[2][128];
  __shared__ float red[8];
  __shared__ float alpha_s[128];
  if (tid < Tn) wx[tid] = fc_w[2*Hn + tid];
  __syncthreads();

  const float* ib = in + (size_t)b*Tn*Kn;
  const int t0 = half*64, t1 = half ? Tn : 64;
  float acc = 0.f;
  for (int t=t0; t<t1; t++) acc += ib[t*Kn + k] * wx[t];
  partial[half][k] = acc;
  __syncthreads();
  const float tot = partial[0][k] + partial[1][k];

  float mx = tot;
#pragma unroll
  for (int o=32;o>0;o>>=1) mx = fmaxf(mx, __shfl_xor(mx, o));
  const int wv = tid >> 6;
  if ((tid & 63) == 0) red[wv] = mx;
  __syncthreads();
  mx = fmaxf(fmaxf(red[0],red[1]), fmaxf(red[2],red[3]));
  float e = __expf(tot - mx);
  float sm = e;
#pragma unroll
  for (int o=32;o>0;o>>=1) sm += __shfl_xor(sm, o);
  if ((tid & 63) == 0) red[4+wv] = sm;
  __syncthreads();
  if (half == 0) alpha_s[k] = e / (red[4] + red[5]);
  __syncthreads();

  const int k4 = tid & 31;
  const int tr = tid >> 5;
  const f32x4 al4 = *(const f32x4*)&alpha_s[k4*4];
  float* ob = out + (size_t)b*Tn*Kn;
  for (int t=tr; t<Tn; t+=8){
    f32x4 v = *(const f32x4*)(ib + t*Kn + k4*4);
    v[0]*=al4[0]; v[1]*=al4[1]; v[2]*=al4[2]; v[3]*=al4[3];
    *(f32x4*)(ob + t*Kn + k4*4) = v;
  }
}

// ---------------- Phase GX: gx = x @ W_ih^T + bias, packed in MFMA C-layout --
__global__ __launch_bounds__(256) void gx_kernel(
    const float* __restrict__ xw, const float* __restrict__ W_ih,
    const __hip_bfloat16* __restrict__ Bih,
    const float* __restrict__ b_ih, const float* __restrict__ b_hh,
    __hip_bfloat16* __restrict__ gx, int pre)
{
  const int g    = blockIdx.x & 31;
  const int tpb  = blockIdx.x >> 5;       // 0..15
  const int tid  = threadIdx.x;
  const int wv   = tid >> 6;
  const int lane = tid & 63;
  const int c    = lane & 15;
  const int quad = lane >> 4;

  const int b  = g*8 + (c & 7);

  s16x8 afr[4][4];
#pragma unroll
  for (int tpi=0; tpi<4; tpi++){
    const int t0 = (tpb*4 + tpi)*2;
    const int tt = min(t0 + (c >> 3), Tn-1);
    const float* xp = xw + ((size_t)b*Tn + tt)*Kn + quad*8;
#pragma unroll
    for (int kb=0; kb<4; kb++)
      afr[tpi][kb] = cvt8(*(const f32x4*)(xp + kb*32), *(const f32x4*)(xp + kb*32 + 4));
  }

  const int tof = (quad >> 1);
  const int mh  = (quad & 1) * 4;

  for (int j = wv*16; j < wv*16+16; j++){
    const int n = j*16 + c;
    const float bias = b_ih[n] + b_hh[n];
    s16x8 bfr[4];
    if (pre){
      const __hip_bfloat16* wp = Bih + (size_t)n*Kn + quad*8;
#pragma unroll
      for (int kb=0; kb<4; kb++) bfr[kb] = *(const s16x8*)(wp + kb*32);
    } else {
      const float* wp = W_ih + (size_t)n*Kn + quad*8;
#pragma unroll
      for (int kb=0; kb<4; kb++)
        bfr[kb] = cvt8(*(const f32x4*)(wp + kb*32), *(const f32x4*)(wp + kb*32 + 4));
    }
    const int G = j >> 4, rem = j & 15, s = rem >> 3, w8 = rem & 7;
#pragma unroll
    for (int tpi=0; tpi<4; tpi++){
      f32x4 acc = {bias, bias, bias, bias};
#pragma unroll
      for (int kb=0; kb<4; kb++)
        acc = __builtin_amdgcn_mfma_f32_16x16x32_bf16(afr[tpi][kb], bfr[kb], acc, 0,0,0);
      const int trow = (tpb*4 + tpi)*2 + tof;
      if (trow < Tn){
        __hip_bfloat16* dst = gx +
          (((((size_t)g*Tn + trow)*2 + s)*8 + w8)*4 + G)*128 + c*8 + mh;
        ushort4 pk;
        pk.x = f2bf_rn(acc[0]); pk.y = f2bf_rn(acc[1]);
        pk.z = f2bf_rn(acc[2]); pk.w = f2bf_rn(acc[3]);
        *(ushort4*)dst = pk;
      }
    }
  }
}

// ---------------- Scan: N-split + mid-step poll, single-u64 tagged record ---
// Record = ONE u64 per thread: two f32 h values, step tag in the low 7
// mantissa bits of each dword (below the hi/lo-bf16 precision the consumer
// reconstructs). Poll = ONE atomic load + waitcnt per iteration (round 9 had
// two serialized -> ~2000-cyc poll period; this halves it).
__global__ __launch_bounds__(512, 2) void scan_kernel(
    const float* __restrict__ W_hh, const __hip_bfloat16* __restrict__ Bhh,
    float* __restrict__ out, const __hip_bfloat16* __restrict__ gx,
    unsigned long long* __restrict__ rec, int pre)
{
  const int bid  = blockIdx.x;
  const int s    = (bid >> 3) & 1;
  const int g    = (bid & 7) | ((bid >> 4) << 3);
  const int b0   = g * 8;
  const int tid  = threadIdx.x;
  const int w    = tid >> 6;
  const int lane = tid & 63;
  const int c    = lane & 15;
  const int quad = lane >> 4;
  const int u    = s*128 + w*16 + c;

  __shared__ __align__(16) unsigned short hhi[2*8*272];
  __shared__ __align__(16) unsigned short hlo[2*8*272];

  // persistent W_hh B-frags, statically indexed: own half + partner half
  s16x8 whO[4][4], whT[4][4];
  if (pre){
#pragma unroll
    for (int G=0; G<4; G++){
      const __hip_bfloat16* pO = Bhh + (size_t)(G*Hn + u)*Hn + s*128     + quad*8;
      const __hip_bfloat16* pT = Bhh + (size_t)(G*Hn + u)*Hn + (1-s)*128 + quad*8;
#pragma unroll
      for (int kb=0; kb<4; kb++){
        whO[G][kb] = *(const s16x8*)(pO + kb*32);
        whT[G][kb] = *(const s16x8*)(pT + kb*32);
      }
    }
  } else {
#pragma unroll
    for (int G=0; G<4; G++){
      const float* pO = W_hh + (size_t)(G*Hn + u)*Hn + s*128     + quad*8;
      const float* pT = W_hh + (size_t)(G*Hn + u)*Hn + (1-s)*128 + quad*8;
#pragma unroll
      for (int kb=0; kb<4; kb++){
        whO[G][kb] = cvt8(*(const f32x4*)(pO + kb*32), *(const f32x4*)(pO + kb*32 + 4));
        whT[G][kb] = cvt8(*(const f32x4*)(pT + kb*32), *(const f32x4*)(pT + kb*32 + 4));
      }
    }
  }

  const int rsel0 = (quad >> 1) * 2;
  const int prr0  = rsel0 ^ 2;
  const int m0    = (quad & 1)*4 + rsel0;
  float cst[2] = {0.f, 0.f};

  const size_t enc_base = (size_t)Bn*Tn*Kn;
  unsigned long long* rec_mine  = rec + ((size_t)g*2 + s)*1024;
  unsigned long long* rec_other = rec + ((size_t)g*2 + (1-s))*1024;

  // remote-fill decode for lane index tid (matches producer packing)
  const int rq   = lane >> 4;
  const int r_m0 = (rq & 1)*4 + (rq >> 1)*2;
  const int r_u  = w*16 + c;
  const int rk   = (1-s)*128 + r_u;

  const __hip_bfloat16* gxg = gx + ((((size_t)g*Tn)*2 + s)*8 + w)*4*128;

  // prologue gx prefetch for t=0
  ushort4 gxr[4];
  if (quad < 2){
    const __hip_bfloat16* gp0 = gxg + c*8 + quad*4;
#pragma unroll
    for (int G=0; G<4; G++) gxr[G] = *(const ushort4*)(gp0 + G*128);
  }

  for (int t=0; t<Tn; t++){
    const int buf  = (t & 1) * 8*272;
    const int nbuf = ((t+1) & 1) * 8*272;

    // ---- acc init from gx (hi rows) ----
    f32x4 acc[4];
#pragma unroll
    for (int G=0; G<4; G++){
      if (quad < 2){
        acc[G][0]=bf2f(gxr[G].x); acc[G][1]=bf2f(gxr[G].y);
        acc[G][2]=bf2f(gxr[G].z); acc[G][3]=bf2f(gxr[G].w);
      } else {
        acc[G][0]=0.f; acc[G][1]=0.f; acc[G][2]=0.f; acc[G][3]=0.f;
      }
    }

    if (t > 0){
      const unsigned short* hb  = (c < 8) ? &hhi[buf + c*272] : &hlo[buf + (c-8)*272];
      const unsigned short* hbO = hb + s*128     + quad*8;   // own K-columns
      const unsigned short* hbT = hb + (1-s)*128 + quad*8;   // partner K-columns

      // ---- own-half MFMAs (no wait; overlaps partner transport) ----
#pragma unroll
      for (int kb=0; kb<4; kb++){
        const s16x8 af = *(const s16x8*)(hbO + kb*32);
        acc[0] = __builtin_amdgcn_mfma_f32_16x16x32_bf16(af, whO[0][kb], acc[0],0,0,0);
        acc[1] = __builtin_amdgcn_mfma_f32_16x16x32_bf16(af, whO[1][kb], acc[1],0,0,0);
        acc[2] = __builtin_amdgcn_mfma_f32_16x16x32_bf16(af, whO[2][kb], acc[2],0,0,0);
        acc[3] = __builtin_amdgcn_mfma_f32_16x16x32_bf16(af, whO[3][kb], acc[3],0,0,0);
      }

      // ---- poll partner h(t-1): slot (t-1)&1, tag t (single load) ----
      {
        const unsigned tg = (unsigned)t & 0x7Fu;
        const unsigned long long* ro = rec_other + (size_t)((t-1) & 1)*512 + tid;
        unsigned long long q;
        for (;;){
          q = __hip_atomic_load(ro, __ATOMIC_RELAXED, __HIP_MEMORY_SCOPE_AGENT);
          if ( (((unsigned)q) & 0x7Fu) == tg &&
               (((unsigned)(q >> 32)) & 0x7Fu) == tg ) break;
        }
        const float rv0 = __uint_as_float((unsigned)q);
        const float rv1 = __uint_as_float((unsigned)(q >> 32));
        const unsigned short vh0 = f2bf_rn(rv0);
        const unsigned short vl0 = f2bf_rn(rv0 - bf2f(vh0));
        const unsigned short vh1 = f2bf_rn(rv1);
        const unsigned short vl1 = f2bf_rn(rv1 - bf2f(vh1));
        hhi[buf + r_m0*272 + rk]     = vh0;
        hlo[buf + r_m0*272 + rk]     = vl0;
        hhi[buf + (r_m0+1)*272 + rk] = vh1;
        hlo[buf + (r_m0+1)*272 + rk] = vl1;
      }
      __syncthreads();   // barrier 2: partner columns visible

      // ---- partner-half MFMAs ----
#pragma unroll
      for (int kb=0; kb<4; kb++){
        const s16x8 af = *(const s16x8*)(hbT + kb*32);
        acc[0] = __builtin_amdgcn_mfma_f32_16x16x32_bf16(af, whT[0][kb], acc[0],0,0,0);
        acc[1] = __builtin_amdgcn_mfma_f32_16x16x32_bf16(af, whT[1][kb], acc[1],0,0,0);
        acc[2] = __builtin_amdgcn_mfma_f32_16x16x32_bf16(af, whT[2][kb], acc[2],0,0,0);
        acc[3] = __builtin_amdgcn_mfma_f32_16x16x32_bf16(af, whT[3][kb], acc[3],0,0,0);
      }
    }

    // ---- epilogue: combine hi/lo via shfl_xor(32); 2 LSTM updates/lane ----
    float hv[2];
#pragma unroll
    for (int rp=0; rp<2; rp++){
      const int rr  = rsel0 + rp;
      const int prr = prr0 + rp;
      const float gi = acc[0][rr] + __shfl_xor(acc[0][prr], 32);
      const float gf = acc[1][rr] + __shfl_xor(acc[1][prr], 32);
      const float gg = acc[2][rr] + __shfl_xor(acc[2][prr], 32);
      const float go = acc[3][rr] + __shfl_xor(acc[3][prr], 32);
      const float cn = sigf(gf)*cst[rp] + sigf(gi)*tanh_fast(gg);
      cst[rp] = cn;
      hv[rp] = sigf(go)*tanh_fast(cn);
    }

    // ---- publish tagged record FIRST (serial path ends here) ----
    if (t < Tn-1){
      const unsigned tg = (unsigned)(t+1) & 0x7Fu;
      const unsigned d0 = (__float_as_uint(hv[0]) & 0xFFFFFF80u) | tg;
      const unsigned d1 = (__float_as_uint(hv[1]) & 0xFFFFFF80u) | tg;
      const unsigned long long q =
          (unsigned long long)d0 | ((unsigned long long)d1 << 32);
      __hip_atomic_store(rec_mine + (size_t)(t & 1)*512 + tid, q,
                         __ATOMIC_RELAXED, __HIP_MEMORY_SCOPE_AGENT);
    }

    // ---- own half of next step's LDS + encode output (overlaps transport) --
#pragma unroll
    for (int rp=0; rp<2; rp++){
      const unsigned short hi = f2bf_rn(hv[rp]);
      const unsigned short lo = f2bf_rn(hv[rp] - bf2f(hi));
      const int m = m0 + rp;
      hhi[nbuf + m*272 + u] = hi;
      hlo[nbuf + m*272 + u] = lo;
      out[enc_base + ((size_t)(b0+m)*Tn + t)*Hn + u] = hv[rp];
    }

    // ---- gx prefetch for t+1 (also overlaps transport) ----
    if (t+1 < Tn && quad < 2){
      const __hip_bfloat16* gp = gxg + (size_t)(t+1)*2*8*4*128 + c*8 + quad*4;
#pragma unroll
      for (int G=0; G<4; G++) gxr[G] = *(const ushort4*)(gp + G*128);
    }

    __syncthreads();   // barrier 1: own columns of nbuf visible
  }
}

extern "C" void kernel_launch(void* const* d_in, const int* in_sizes, int n_in,
                              void* d_out, int out_size, void* d_ws, size_t ws_size,
                              hipStream_t stream) {
  const float* input = (const float*)d_in[0];
  const float* W_ih  = (const float*)d_in[1];
  const float* W_hh  = (const float*)d_in[2];
  const float* b_ih  = (const float*)d_in[3];
  const float* b_hh  = (const float*)d_in[4];
  const float* fc_w  = (const float*)d_in[5];
  float* out = (float*)d_out;

  char* wsb = (char*)d_ws;
  __hip_bfloat16* gxp = (__hip_bfloat16*)wsb;
  unsigned long long* rec = (unsigned long long*)(wsb + REC_OFF);

  const int full = (ws_size >= WS_NEED) ? 1 : 0;
  __hip_bfloat16* Bih = full ? (__hip_bfloat16*)(wsb + WIH_OFF) : (__hip_bfloat16*)W_ih;
  __hip_bfloat16* Bhh = full ? (__hip_bfloat16*)(wsb + WHH_OFF) : (__hip_bfloat16*)W_hh;

  hipMemsetAsync(rec, 0, REC_BYTES, stream);
  if (full)
    wconv_kernel<<<192, 256, 0, stream>>>(W_ih, W_hh, Bih, Bhh);
  phase0_kernel<<<Bn, 256, 0, stream>>>(input, fc_w, out);
  gx_kernel<<<512, 256, 0, stream>>>(out, W_ih, Bih, b_ih, b_hh, gxp, full);
  scan_kernel<<<64, 512, 0, stream>>>(W_hh, Bhh, out, gxp, rec, full);
}

// Round 11
// 426.616 us; speedup vs baseline: 1.0279x; 1.0279x over previous
//
#include <hip/hip_runtime.h>
#include <hip/hip_bf16.h>
#include <stdint.h>

#define Bn 256
#define Tn 127
#define Kn 128
#define Hn 256

typedef float f32x4 __attribute__((ext_vector_type(4)));
typedef short s16x8 __attribute__((ext_vector_type(8)));

// ws layout
#define GX_BYTES   66584576ULL   // bf16 [32][127][2][8][4][128]
#define REC_OFF    66584576ULL   // u64 [32 g][2 s][2 parity][512 tid] tagged records
#define REC_BYTES  524288ULL
#define WIH_OFF    (REC_OFF + REC_BYTES)     // bf16 W_ih, 256KB
#define WHH_OFF    (WIH_OFF + 262144ULL)     // bf16 W_hh, 512KB
#define WS_NEED    (WHH_OFF + 524288ULL)

// LDS-only barrier: drain lgkm (ds ops) but NOT vmcnt -- __syncthreads would
// emit s_waitcnt vmcnt(0) and serialize HBM store-acks into every step.
#define LDS_BARRIER() asm volatile("s_waitcnt lgkmcnt(0)\n\ts_barrier" ::: "memory")

__device__ __forceinline__ float bf2f(unsigned short b){
  union { unsigned u; float f; } v; v.u = ((unsigned)b) << 16; return v.f;
}
__device__ __forceinline__ unsigned short f2bf_rn(float f){
  union { __hip_bfloat16 h; unsigned short s; } u;
  u.h = __float2bfloat16(f);
  return u.s;
}
__device__ __forceinline__ s16x8 cvt8(f32x4 a, f32x4 b){
  union { __hip_bfloat162 h2; unsigned short s[2]; } u0,u1,u2,u3;
  u0.h2 = __float22bfloat162_rn(float2{a[0],a[1]});
  u1.h2 = __float22bfloat162_rn(float2{a[2],a[3]});
  u2.h2 = __float22bfloat162_rn(float2{b[0],b[1]});
  u3.h2 = __float22bfloat162_rn(float2{b[2],b[3]});
  s16x8 r;
  r[0]=(short)u0.s[0]; r[1]=(short)u0.s[1]; r[2]=(short)u1.s[0]; r[3]=(short)u1.s[1];
  r[4]=(short)u2.s[0]; r[5]=(short)u2.s[1]; r[6]=(short)u3.s[0]; r[7]=(short)u3.s[1];
  return r;
}
__device__ __forceinline__ float sigf(float x){ return 1.f/(1.f+__expf(-x)); }
__device__ __forceinline__ float tanh_fast(float x){
  float ax = fabsf(x);
  float e = __expf(-2.f*ax);
  float t = (1.f - e)/(1.f + e);
  return x < 0.f ? -t : t;
}

// ---------------- W conversion: f32 -> bf16, once per launch ----------------
__global__ __launch_bounds__(256) void wconv_kernel(
    const float* __restrict__ Wih, const float* __restrict__ Whh,
    __hip_bfloat16* __restrict__ Bih, __hip_bfloat16* __restrict__ Bhh)
{
  const int i = blockIdx.x*256 + threadIdx.x;   // grid 192*256 = 49152
  const float* src; __hip_bfloat16* dst; int j;
  if (i < 16384){ src = Wih; dst = Bih; j = i; }
  else          { src = Whh; dst = Bhh; j = i - 16384; }
  const f32x4 a = *(const f32x4*)(src + (size_t)j*8);
  const f32x4 b = *(const f32x4*)(src + (size_t)j*8 + 4);
  s16x8 r = cvt8(a, b);
  *(s16x8*)(dst + (size_t)j*8) = r;
}

// ---------------- Phase 0: alpha = softmax(x_score), weight = alpha*input -----
__global__ __launch_bounds__(256) void phase0_kernel(
    const float* __restrict__ in, const float* __restrict__ fc_w,
    float* __restrict__ out)
{
  const int b    = blockIdx.x;
  const int tid  = threadIdx.x;
  const int k    = tid & 127;
  const int half = tid >> 7;
  __shared__ float wx[Tn+1];
  __shared__ float partial[2][128];
  __shared__ float red[8];
  __shared__ float alpha_s[128];
  if (tid < Tn) wx[tid] = fc_w[2*Hn + tid];
  __syncthreads();

  const float* ib = in + (size_t)b*Tn*Kn;
  const int t0 = half*64, t1 = half ? Tn : 64;
  float acc = 0.f;
  for (int t=t0; t<t1; t++) acc += ib[t*Kn + k] * wx[t];
  partial[half][k] = acc;
  __syncthreads();
  const float tot = partial[0][k] + partial[1][k];

  float mx = tot;
#pragma unroll
  for (int o=32;o>0;o>>=1) mx = fmaxf(mx, __shfl_xor(mx, o));
  const int wv = tid >> 6;
  if ((tid & 63) == 0) red[wv] = mx;
  __syncthreads();
  mx = fmaxf(fmaxf(red[0],red[1]), fmaxf(red[2],red[3]));
  float e = __expf(tot - mx);
  float sm = e;
#pragma unroll
  for (int o=32;o>0;o>>=1) sm += __shfl_xor(sm, o);
  if ((tid & 63) == 0) red[4+wv] = sm;
  __syncthreads();
  if (half == 0) alpha_s[k] = e / (red[4] + red[5]);
  __syncthreads();

  const int k4 = tid & 31;
  const int tr = tid >> 5;
  const f32x4 al4 = *(const f32x4*)&alpha_s[k4*4];
  float* ob = out + (size_t)b*Tn*Kn;
  for (int t=tr; t<Tn; t+=8){
    f32x4 v = *(const f32x4*)(ib + t*Kn + k4*4);
    v[0]*=al4[0]; v[1]*=al4[1]; v[2]*=al4[2]; v[3]*=al4[3];
    *(f32x4*)(ob + t*Kn + k4*4) = v;
  }
}

// ---------------- Phase GX: gx = x @ W_ih^T + bias, packed in MFMA C-layout --
__global__ __launch_bounds__(256) void gx_kernel(
    const float* __restrict__ xw, const float* __restrict__ W_ih,
    const __hip_bfloat16* __restrict__ Bih,
    const float* __restrict__ b_ih, const float* __restrict__ b_hh,
    __hip_bfloat16* __restrict__ gx, int pre)
{
  const int g    = blockIdx.x & 31;
  const int tpb  = blockIdx.x >> 5;       // 0..15
  const int tid  = threadIdx.x;
  const int wv   = tid >> 6;
  const int lane = tid & 63;
  const int c    = lane & 15;
  const int quad = lane >> 4;

  const int b  = g*8 + (c & 7);

  s16x8 afr[4][4];
#pragma unroll
  for (int tpi=0; tpi<4; tpi++){
    const int t0 = (tpb*4 + tpi)*2;
    const int tt = min(t0 + (c >> 3), Tn-1);
    const float* xp = xw + ((size_t)b*Tn + tt)*Kn + quad*8;
#pragma unroll
    for (int kb=0; kb<4; kb++)
      afr[tpi][kb] = cvt8(*(const f32x4*)(xp + kb*32), *(const f32x4*)(xp + kb*32 + 4));
  }

  const int tof = (quad >> 1);
  const int mh  = (quad & 1) * 4;

  for (int j = wv*16; j < wv*16+16; j++){
    const int n = j*16 + c;
    const float bias = b_ih[n] + b_hh[n];
    s16x8 bfr[4];
    if (pre){
      const __hip_bfloat16* wp = Bih + (size_t)n*Kn + quad*8;
#pragma unroll
      for (int kb=0; kb<4; kb++) bfr[kb] = *(const s16x8*)(wp + kb*32);
    } else {
      const float* wp = W_ih + (size_t)n*Kn + quad*8;
#pragma unroll
      for (int kb=0; kb<4; kb++)
        bfr[kb] = cvt8(*(const f32x4*)(wp + kb*32), *(const f32x4*)(wp + kb*32 + 4));
    }
    const int G = j >> 4, rem = j & 15, s = rem >> 3, w8 = rem & 7;
#pragma unroll
    for (int tpi=0; tpi<4; tpi++){
      f32x4 acc = {bias, bias, bias, bias};
#pragma unroll
      for (int kb=0; kb<4; kb++)
        acc = __builtin_amdgcn_mfma_f32_16x16x32_bf16(afr[tpi][kb], bfr[kb], acc, 0,0,0);
      const int trow = (tpb*4 + tpi)*2 + tof;
      if (trow < Tn){
        __hip_bfloat16* dst = gx +
          (((((size_t)g*Tn + trow)*2 + s)*8 + w8)*4 + G)*128 + c*8 + mh;
        ushort4 pk;
        pk.x = f2bf_rn(acc[0]); pk.y = f2bf_rn(acc[1]);
        pk.z = f2bf_rn(acc[2]); pk.w = f2bf_rn(acc[3]);
        *(ushort4*)dst = pk;
      }
    }
  }
}

// ---------------- Scan: N-split + mid-step poll + LDS-only barriers ---------
// Step order: acc-init (no wait) -> issue gx prefetch (absorbed by poll's
// vmcnt0) -> own-half MFMAs -> poll partner h(t-1) -> remote fill ->
// LDS_BARRIER -> partner-half MFMAs -> epilogue -> publish -> own fill ->
// out stores -> LDS_BARRIER. Stores issue last and retire during the next
// step's compute+poll window instead of stalling a vmcnt(0) barrier drain.
__global__ __launch_bounds__(512, 2) void scan_kernel(
    const float* __restrict__ W_hh, const __hip_bfloat16* __restrict__ Bhh,
    float* __restrict__ out, const __hip_bfloat16* __restrict__ gx,
    unsigned long long* __restrict__ rec, int pre)
{
  const int bid  = blockIdx.x;
  const int s    = (bid >> 3) & 1;
  const int g    = (bid & 7) | ((bid >> 4) << 3);
  const int b0   = g * 8;
  const int tid  = threadIdx.x;
  const int w    = tid >> 6;
  const int lane = tid & 63;
  const int c    = lane & 15;
  const int quad = lane >> 4;
  const int u    = s*128 + w*16 + c;

  __shared__ __align__(16) unsigned short hhi[2*8*272];
  __shared__ __align__(16) unsigned short hlo[2*8*272];

  // persistent W_hh B-frags, statically indexed: own half + partner half
  s16x8 whO[4][4], whT[4][4];
  if (pre){
#pragma unroll
    for (int G=0; G<4; G++){
      const __hip_bfloat16* pO = Bhh + (size_t)(G*Hn + u)*Hn + s*128     + quad*8;
      const __hip_bfloat16* pT = Bhh + (size_t)(G*Hn + u)*Hn + (1-s)*128 + quad*8;
#pragma unroll
      for (int kb=0; kb<4; kb++){
        whO[G][kb] = *(const s16x8*)(pO + kb*32);
        whT[G][kb] = *(const s16x8*)(pT + kb*32);
      }
    }
  } else {
#pragma unroll
    for (int G=0; G<4; G++){
      const float* pO = W_hh + (size_t)(G*Hn + u)*Hn + s*128     + quad*8;
      const float* pT = W_hh + (size_t)(G*Hn + u)*Hn + (1-s)*128 + quad*8;
#pragma unroll
      for (int kb=0; kb<4; kb++){
        whO[G][kb] = cvt8(*(const f32x4*)(pO + kb*32), *(const f32x4*)(pO + kb*32 + 4));
        whT[G][kb] = cvt8(*(const f32x4*)(pT + kb*32), *(const f32x4*)(pT + kb*32 + 4));
      }
    }
  }

  const int rsel0 = (quad >> 1) * 2;
  const int prr0  = rsel0 ^ 2;
  const int m0    = (quad & 1)*4 + rsel0;
  float cst[2] = {0.f, 0.f};

  const size_t enc_base = (size_t)Bn*Tn*Kn;
  unsigned long long* rec_mine  = rec + ((size_t)g*2 + s)*1024;
  unsigned long long* rec_other = rec + ((size_t)g*2 + (1-s))*1024;

  // remote-fill decode for lane index tid (matches producer packing)
  const int rq   = lane >> 4;
  const int r_m0 = (rq & 1)*4 + (rq >> 1)*2;
  const int r_u  = w*16 + c;
  const int rk   = (1-s)*128 + r_u;

  const __hip_bfloat16* gxg = gx + ((((size_t)g*Tn)*2 + s)*8 + w)*4*128;

  // prologue gx prefetch for t=0
  ushort4 gxr[4];
  if (quad < 2){
    const __hip_bfloat16* gp0 = gxg + c*8 + quad*4;
#pragma unroll
    for (int G=0; G<4; G++) gxr[G] = *(const ushort4*)(gp0 + G*128);
  }

  for (int t=0; t<Tn; t++){
    const int buf  = (t & 1) * 8*272;
    const int nbuf = ((t+1) & 1) * 8*272;

    // ---- acc init from gx (hi rows); gxr drained by last step's poll ----
    f32x4 acc[4];
#pragma unroll
    for (int G=0; G<4; G++){
      if (quad < 2){
        acc[G][0]=bf2f(gxr[G].x); acc[G][1]=bf2f(gxr[G].y);
        acc[G][2]=bf2f(gxr[G].z); acc[G][3]=bf2f(gxr[G].w);
      } else {
        acc[G][0]=0.f; acc[G][1]=0.f; acc[G][2]=0.f; acc[G][3]=0.f;
      }
    }

    // ---- issue gx prefetch for t+1 EARLY (absorbed under the poll) ----
    if (t+1 < Tn && quad < 2){
      const __hip_bfloat16* gp = gxg + (size_t)(t+1)*2*8*4*128 + c*8 + quad*4;
#pragma unroll
      for (int G=0; G<4; G++) gxr[G] = *(const ushort4*)(gp + G*128);
    }

    if (t > 0){
      const unsigned short* hb  = (c < 8) ? &hhi[buf + c*272] : &hlo[buf + (c-8)*272];
      const unsigned short* hbO = hb + s*128     + quad*8;   // own K-columns
      const unsigned short* hbT = hb + (1-s)*128 + quad*8;   // partner K-columns

      // ---- own-half MFMAs (no wait; overlaps partner transport) ----
#pragma unroll
      for (int kb=0; kb<4; kb++){
        const s16x8 af = *(const s16x8*)(hbO + kb*32);
        acc[0] = __builtin_amdgcn_mfma_f32_16x16x32_bf16(af, whO[0][kb], acc[0],0,0,0);
        acc[1] = __builtin_amdgcn_mfma_f32_16x16x32_bf16(af, whO[1][kb], acc[1],0,0,0);
        acc[2] = __builtin_amdgcn_mfma_f32_16x16x32_bf16(af, whO[2][kb], acc[2],0,0,0);
        acc[3] = __builtin_amdgcn_mfma_f32_16x16x32_bf16(af, whO[3][kb], acc[3],0,0,0);
      }

      // ---- poll partner h(t-1): slot (t-1)&1, tag t (single load) ----
      {
        const unsigned tg = (unsigned)t & 0x7Fu;
        const unsigned long long* ro = rec_other + (size_t)((t-1) & 1)*512 + tid;
        unsigned long long q;
        for (;;){
          q = __hip_atomic_load(ro, __ATOMIC_RELAXED, __HIP_MEMORY_SCOPE_AGENT);
          if ( (((unsigned)q) & 0x7Fu) == tg &&
               (((unsigned)(q >> 32)) & 0x7Fu) == tg ) break;
        }
        const float rv0 = __uint_as_float((unsigned)q);
        const float rv1 = __uint_as_float((unsigned)(q >> 32));
        const unsigned short vh0 = f2bf_rn(rv0);
        const unsigned short vl0 = f2bf_rn(rv0 - bf2f(vh0));
        const unsigned short vh1 = f2bf_rn(rv1);
        const unsigned short vl1 = f2bf_rn(rv1 - bf2f(vh1));
        hhi[buf + r_m0*272 + rk]     = vh0;
        hlo[buf + r_m0*272 + rk]     = vl0;
        hhi[buf + (r_m0+1)*272 + rk] = vh1;
        hlo[buf + (r_m0+1)*272 + rk] = vl1;
      }
      LDS_BARRIER();   // barrier 2: partner columns visible (LDS-only drain)

      // ---- partner-half MFMAs ----
#pragma unroll
      for (int kb=0; kb<4; kb++){
        const s16x8 af = *(const s16x8*)(hbT + kb*32);
        acc[0] = __builtin_amdgcn_mfma_f32_16x16x32_bf16(af, whT[0][kb], acc[0],0,0,0);
        acc[1] = __builtin_amdgcn_mfma_f32_16x16x32_bf16(af, whT[1][kb], acc[1],0,0,0);
        acc[2] = __builtin_amdgcn_mfma_f32_16x16x32_bf16(af, whT[2][kb], acc[2],0,0,0);
        acc[3] = __builtin_amdgcn_mfma_f32_16x16x32_bf16(af, whT[3][kb], acc[3],0,0,0);
      }
    }

    // ---- epilogue: combine hi/lo via shfl_xor(32); 2 LSTM updates/lane ----
    float hv[2];
#pragma unroll
    for (int rp=0; rp<2; rp++){
      const int rr  = rsel0 + rp;
      const int prr = prr0 + rp;
      const float gi = acc[0][rr] + __shfl_xor(acc[0][prr], 32);
      const float gf = acc[1][rr] + __shfl_xor(acc[1][prr], 32);
      const float gg = acc[2][rr] + __shfl_xor(acc[2][prr], 32);
      const float go = acc[3][rr] + __shfl_xor(acc[3][prr], 32);
      const float cn = sigf(gf)*cst[rp] + sigf(gi)*tanh_fast(gg);
      cst[rp] = cn;
      hv[rp] = sigf(go)*tanh_fast(cn);
    }

    // ---- publish tagged record FIRST (serial path ends here) ----
    if (t < Tn-1){
      const unsigned tg = (unsigned)(t+1) & 0x7Fu;
      const unsigned d0 = (__float_as_uint(hv[0]) & 0xFFFFFF80u) | tg;
      const unsigned d1 = (__float_as_uint(hv[1]) & 0xFFFFFF80u) | tg;
      const unsigned long long q =
          (unsigned long long)d0 | ((unsigned long long)d1 << 32);
      __hip_atomic_store(rec_mine + (size_t)(t & 1)*512 + tid, q,
                         __ATOMIC_RELAXED, __HIP_MEMORY_SCOPE_AGENT);
    }

    // ---- own half of next step's LDS (ds writes) ----
    unsigned short hi2[2], lo2[2];
#pragma unroll
    for (int rp=0; rp<2; rp++){
      hi2[rp] = f2bf_rn(hv[rp]);
      lo2[rp] = f2bf_rn(hv[rp] - bf2f(hi2[rp]));
      const int m = m0 + rp;
      hhi[nbuf + m*272 + u] = hi2[rp];
      hlo[nbuf + m*272 + u] = lo2[rp];
    }

    // ---- encode output stores LAST (retire during next step's window) ----
#pragma unroll
    for (int rp=0; rp<2; rp++){
      const int m = m0 + rp;
      out[enc_base + ((size_t)(b0+m)*Tn + t)*Hn + u] = hv[rp];
    }

    LDS_BARRIER();   // barrier 1: own columns of nbuf visible (LDS-only drain)
  }
}

extern "C" void kernel_launch(void* const* d_in, const int* in_sizes, int n_in,
                              void* d_out, int out_size, void* d_ws, size_t ws_size,
                              hipStream_t stream) {
  const float* input = (const float*)d_in[0];
  const float* W_ih  = (const float*)d_in[1];
  const float* W_hh  = (const float*)d_in[2];
  const float* b_ih  = (const float*)d_in[3];
  const float* b_hh  = (const float*)d_in[4];
  const float* fc_w  = (const float*)d_in[5];
  float* out = (float*)d_out;

  char* wsb = (char*)d_ws;
  __hip_bfloat16* gxp = (__hip_bfloat16*)wsb;
  unsigned long long* rec = (unsigned long long*)(wsb + REC_OFF);

  const int full = (ws_size >= WS_NEED) ? 1 : 0;
  __hip_bfloat16* Bih = full ? (__hip_bfloat16*)(wsb + WIH_OFF) : (__hip_bfloat16*)W_ih;
  __hip_bfloat16* Bhh = full ? (__hip_bfloat16*)(wsb + WHH_OFF) : (__hip_bfloat16*)W_hh;

  hipMemsetAsync(rec, 0, REC_BYTES, stream);
  if (full)
    wconv_kernel<<<192, 256, 0, stream>>>(W_ih, W_hh, Bih, Bhh);
  phase0_kernel<<<Bn, 256, 0, stream>>>(input, fc_w, out);
  gx_kernel<<<512, 256, 0, stream>>>(out, W_ih, Bih, b_ih, b_hh, gxp, full);
  scan_kernel<<<64, 512, 0, stream>>>(W_hh, Bhh, out, gxp, rec, full);
}